// Round 2
// baseline (110.266 us; speedup 1.0000x reference)
//
#include <hip/hip_runtime.h>

// EdgeNetwork: messages[e,i] = sum_j relu(edges[e,:] @ W[:, i*32+j] + b[i*32+j]) * states[e,j]
// M = 65536 rows, F=16, D=32.  bf16 MFMA 32x32x16 (K=16==F), swapped operands:
// D[j][e] = sum_f W[f][n*32+j] * edges[e][f]; lane owns one edge (col=lane&31),
// 16 j-values in acc regs (row=(r&3)+8*(r>>2)+4*(lane>>5)) -> relu*state reduce
// is 16 in-register FMAs + one shfl_xor(32).
//
// Round-2 changes: (1) prep kernel pre-converts W->bf16 A-frag order + bias->C-frag
// order into d_ws (no per-block staging, no LDS, no barrier in main kernel);
// (2) lanes keep only the 8 msg values they store (select by (k>>3)==h) -> no spills;
// (3) tile split across 2 waves (16 n each), grid 1024x256 -> 4 blocks/CU.

typedef __attribute__((ext_vector_type(8))) short short8;
typedef __attribute__((ext_vector_type(16))) float f32x16;

#define WS_BYTES 36864   // 32768 B Wfrag (bf16) + 4096 B Bfrag (f32)

__device__ __forceinline__ unsigned short f2bf(float x) {
    union { float f; unsigned u; } v; v.f = x;
    unsigned r = (v.u + 0x7FFFu + ((v.u >> 16) & 1u)) >> 16;  // RNE
    return (unsigned short)r;
}

// ---- shared per-wave compute ----
// wf: A-fragment-ordered bf16 W  (idx ((n*64+lane)*8 + t), generic ptr: global or LDS)
// bf: C-fragment-ordered f32 bias (idx n*32 + h*16 + r)
__device__ __forceinline__ void tile_compute(
    const float* __restrict__ states, const float* __restrict__ edges,
    float* __restrict__ out,
    const unsigned short* wf, const float* bf,
    int tile, int nbase, int lane)
{
    const int ecol = lane & 31;
    const int h    = lane >> 5;
    const long long row = (long long)tile * 32 + ecol;

    // edges row -> B fragment: B[k=h*8+t][col=ecol] = edges[row][h*8+t]
    const float* ep = edges + row * 16 + h * 8;
    const float4 ev0 = *reinterpret_cast<const float4*>(ep);
    const float4 ev1 = *reinterpret_cast<const float4*>(ep + 4);
    short8 bfrag;
    bfrag[0] = (short)f2bf(ev0.x); bfrag[1] = (short)f2bf(ev0.y);
    bfrag[2] = (short)f2bf(ev0.z); bfrag[3] = (short)f2bf(ev0.w);
    bfrag[4] = (short)f2bf(ev1.x); bfrag[5] = (short)f2bf(ev1.y);
    bfrag[6] = (short)f2bf(ev1.z); bfrag[7] = (short)f2bf(ev1.w);

    // states aligned with acc reg r: s[r] = states[row][(r>>2)*8 + h*4 + (r&3)]
    const float* sp = states + row * 32 + h * 4;
    const float4 sv0 = *reinterpret_cast<const float4*>(sp);
    const float4 sv1 = *reinterpret_cast<const float4*>(sp + 8);
    const float4 sv2 = *reinterpret_cast<const float4*>(sp + 16);
    const float4 sv3 = *reinterpret_cast<const float4*>(sp + 24);
    const float s[16] = {sv0.x, sv0.y, sv0.z, sv0.w,
                         sv1.x, sv1.y, sv1.z, sv1.w,
                         sv2.x, sv2.y, sv2.z, sv2.w,
                         sv3.x, sv3.y, sv3.z, sv3.w};

    float msg8[8];
    #pragma unroll
    for (int k = 0; k < 16; ++k) {
        const int n = nbase + k;
        const short8 afrag = *reinterpret_cast<const short8*>(wf + (n * 64 + lane) * 8);

        const float* bb = bf + n * 32 + h * 16;
        const float4 c0 = *reinterpret_cast<const float4*>(bb);
        const float4 c1 = *reinterpret_cast<const float4*>(bb + 4);
        const float4 c2 = *reinterpret_cast<const float4*>(bb + 8);
        const float4 c3 = *reinterpret_cast<const float4*>(bb + 12);
        f32x16 acc;
        acc[0]=c0.x;  acc[1]=c0.y;  acc[2]=c0.z;  acc[3]=c0.w;
        acc[4]=c1.x;  acc[5]=c1.y;  acc[6]=c1.z;  acc[7]=c1.w;
        acc[8]=c2.x;  acc[9]=c2.y;  acc[10]=c2.z; acc[11]=c2.w;
        acc[12]=c3.x; acc[13]=c3.y; acc[14]=c3.z; acc[15]=c3.w;

        acc = __builtin_amdgcn_mfma_f32_32x32x16_bf16(afrag, bfrag, acc, 0, 0, 0);

        float p0 = 0.f, p1 = 0.f, p2 = 0.f, p3 = 0.f;
        #pragma unroll
        for (int r = 0; r < 16; r += 4) {
            p0 = fmaf(fmaxf(acc[r+0], 0.f), s[r+0], p0);
            p1 = fmaf(fmaxf(acc[r+1], 0.f), s[r+1], p1);
            p2 = fmaf(fmaxf(acc[r+2], 0.f), s[r+2], p2);
            p3 = fmaf(fmaxf(acc[r+3], 0.f), s[r+3], p3);
        }
        float p = (p0 + p1) + (p2 + p3);
        p += __shfl_xor(p, 32);             // combine the two half-wave j-sets
        if ((k >> 3) == h) msg8[k & 7] = p; // keep only what this lane stores
    }

    // lane stores columns [nbase + h*8, nbase + h*8 + 8)
    float* op = out + row * 32 + nbase + h * 8;
    *reinterpret_cast<float4*>(op)     = make_float4(msg8[0], msg8[1], msg8[2], msg8[3]);
    *reinterpret_cast<float4*>(op + 4) = make_float4(msg8[4], msg8[5], msg8[6], msg8[7]);
}

// ---- prep: W -> bf16 A-frag order, bias -> f32 C-frag order, into ws ----
__global__ __launch_bounds__(256)
void edgenet_prep(const float* __restrict__ W, const float* __restrict__ bias,
                  void* __restrict__ ws)
{
    const int idx = blockIdx.x * 256 + threadIdx.x;   // grid 68*256 = 17408 exact
    unsigned short* wf = (unsigned short*)ws;
    float* bf = (float*)((char*)ws + 32768);
    if (idx < 16384) {
        const int f = idx >> 10, c = idx & 1023, n = c >> 5, j = c & 31;
        wf[((n << 6) + j + ((f >> 3) << 5)) * 8 + (f & 7)] = f2bf(W[idx]);
    } else {
        const int t = idx - 16384;                    // 0..1023
        const int r = t & 15, hh = (t >> 4) & 1, n = t >> 5;
        bf[t] = bias[n * 32 + (r & 3) + ((r >> 2) << 3) + (hh << 2)];
    }
}

// ---- main: no LDS, no barrier; afrag/bias from L2-resident ws ----
__global__ __launch_bounds__(256, 4)
void edgenet_main(const float* __restrict__ states, const float* __restrict__ edges,
                  float* __restrict__ out, const void* __restrict__ ws)
{
    const unsigned short* wf = (const unsigned short*)ws;
    const float* bf = (const float*)((const char*)ws + 32768);
    const int wave = threadIdx.x >> 6;
    const int lane = threadIdx.x & 63;
    const int tile  = blockIdx.x * 2 + (wave >> 1);   // 1024 blocks * 2 = 2048 tiles
    const int nbase = (wave & 1) * 16;
    tile_compute(states, edges, out, wf, bf, tile, nbase, lane);
}

// ---- fallback (ws too small): per-block LDS staging, same math ----
__global__ __launch_bounds__(512)
void edgenet_fallback(const float* __restrict__ states, const float* __restrict__ edges,
                      const float* __restrict__ W, const float* __restrict__ bias,
                      float* __restrict__ out)
{
    __shared__ unsigned short Wlds[16384];
    __shared__ float Blds[1024];
    const int tid = threadIdx.x;
    #pragma unroll
    for (int it = 0; it < 32; ++it) {
        int m = it * 512 + tid;
        int f = m >> 10, c = m & 1023, n = c >> 5, j = c & 31;
        Wlds[((n << 6) + j + ((f >> 3) << 5)) * 8 + (f & 7)] = f2bf(W[m]);
    }
    #pragma unroll
    for (int it = 0; it < 2; ++it) {
        int idx = it * 512 + tid;
        int r = idx & 15, hh = (idx >> 4) & 1, n = idx >> 5;
        Blds[idx] = bias[n * 32 + (r & 3) + ((r >> 2) << 3) + (hh << 2)];
    }
    __syncthreads();
    const int wave = tid >> 6, lane = tid & 63;
    const int tile  = blockIdx.x * 4 + (wave >> 1);   // 512 blocks * 4 = 2048 tiles
    const int nbase = (wave & 1) * 16;
    tile_compute(states, edges, out, Wlds, Blds, tile, nbase, lane);
}

extern "C" void kernel_launch(void* const* d_in, const int* in_sizes, int n_in,
                              void* d_out, int out_size, void* d_ws, size_t ws_size,
                              hipStream_t stream) {
    (void)in_sizes; (void)n_in; (void)out_size;
    const float* states = (const float*)d_in[0];
    const float* edges  = (const float*)d_in[1];
    const float* W      = (const float*)d_in[2];
    const float* bias   = (const float*)d_in[3];
    float* out          = (float*)d_out;

    if (ws_size >= (size_t)WS_BYTES) {
        hipLaunchKernelGGL(edgenet_prep, dim3(68), dim3(256), 0, stream, W, bias, d_ws);
        hipLaunchKernelGGL(edgenet_main, dim3(1024), dim3(256), 0, stream,
                           states, edges, out, d_ws);
    } else {
        hipLaunchKernelGGL(edgenet_fallback, dim3(512), dim3(512), 0, stream,
                           states, edges, W, bias, out);
    }
}

// Round 3
// 20.927 us; speedup vs baseline: 5.2692x; 5.2692x over previous
//
#include <hip/hip_runtime.h>

// EdgeNetwork: messages[e,i] = sum_j relu(edges[e,:] @ W[:, i*32+j] + b[i*32+j]) * states[e,j]
// M = 65536 rows, F=16, D=32.  bf16 MFMA 32x32x16 (K=16==F), swapped operands:
// D[j][e] = sum_f W[f][n*32+j] * edges[e][f]; lane owns one edge (col=lane&31),
// 16 j-values in acc regs (row=(r&3)+8*(r>>2)+4*(lane>>5)) -> relu*state reduce
// is 16 in-register FMAs + one shfl_xor(32).
//
// Round-3 changes (anti-spill): two 8-k loops with store between them so msg[]
// is 8 regs reused (round-2's 64-VGPR clamp caused ~220 MB scratch traffic);
// W/bias back in LDS (bias init = broadcast ds_read, not L2 round-trips);
// __launch_bounds__(512,2) -> 256-VGPR budget, LDS caps occupancy anyway.

typedef __attribute__((ext_vector_type(8))) short short8;
typedef __attribute__((ext_vector_type(16))) float f32x16;

__device__ __forceinline__ unsigned short f2bf(float x) {
    union { float f; unsigned u; } v; v.f = x;
    return (unsigned short)((v.u + 0x7FFFu + ((v.u >> 16) & 1u)) >> 16);  // RNE
}

__global__ __launch_bounds__(512, 2)
void edgenet_kernel(const float* __restrict__ states,
                    const float* __restrict__ edges,
                    const float* __restrict__ W,
                    const float* __restrict__ bias,
                    float* __restrict__ out)
{
    // Wlds: A-frag order, idx ((n*64 + lane)*8 + t); lane l encodes (j=l&31, f=(l>>5)*8+t)
    __shared__ unsigned short Wlds[16384];   // 32 KB
    // Blds: C-frag order, idx n*32 + h*16 + r  ->  bias[n*32 + (r&3) + 8*(r>>2) + 4*h]
    __shared__ float Blds[1024];             // 4 KB

    const int tid  = threadIdx.x;
    const int wave = tid >> 6;
    const int lane = tid & 63;
    const int ecol = lane & 31;
    const int h    = lane >> 5;

    const int tile  = blockIdx.x * 4 + (wave >> 1);   // 512 blocks * 4 = 2048 tiles
    const int nbase = (wave & 1) << 4;                // 0 or 16
    const long long row = (long long)tile * 32 + ecol;

    // ---- prefetch this lane's edges + states (hide HBM latency under staging) ----
    const float* ep = edges + row * 16 + h * 8;
    const float4 ev0 = *reinterpret_cast<const float4*>(ep);
    const float4 ev1 = *reinterpret_cast<const float4*>(ep + 4);
    const float* sp = states + row * 32 + h * 4;
    const float4 sv0 = *reinterpret_cast<const float4*>(sp);
    const float4 sv1 = *reinterpret_cast<const float4*>(sp + 8);
    const float4 sv2 = *reinterpret_cast<const float4*>(sp + 16);
    const float4 sv3 = *reinterpret_cast<const float4*>(sp + 24);

    // ---- stage W (bf16, A-frag order) + bias (C-frag order) into LDS ----
    #pragma unroll
    for (int it = 0; it < 32; ++it) {
        int m = it * 512 + tid;            // coalesced over W[16][1024]
        int f = m >> 10, c = m & 1023, n = c >> 5, j = c & 31;
        Wlds[((n << 6) + j + ((f >> 3) << 5)) * 8 + (f & 7)] = f2bf(W[m]);
    }
    {
        int i0 = tid;
        int r = i0 & 15, hh = (i0 >> 4) & 1, n = i0 >> 5;
        Blds[i0] = bias[(n << 5) + (r & 3) + ((r >> 2) << 3) + (hh << 2)];
        int i1 = tid + 512;
        r = i1 & 15; hh = (i1 >> 4) & 1; n = i1 >> 5;
        Blds[i1] = bias[(n << 5) + (r & 3) + ((r >> 2) << 3) + (hh << 2)];
    }
    __syncthreads();

    // ---- B fragment: B[k=h*8+t][col=ecol] = edges[row][h*8+t] ----
    short8 bfrag;
    bfrag[0] = (short)f2bf(ev0.x); bfrag[1] = (short)f2bf(ev0.y);
    bfrag[2] = (short)f2bf(ev0.z); bfrag[3] = (short)f2bf(ev0.w);
    bfrag[4] = (short)f2bf(ev1.x); bfrag[5] = (short)f2bf(ev1.y);
    bfrag[6] = (short)f2bf(ev1.z); bfrag[7] = (short)f2bf(ev1.w);

    // s[r] = states[row][(r>>2)*8 + h*4 + (r&3)]  (matches acc reg r)
    const float s[16] = {sv0.x, sv0.y, sv0.z, sv0.w,
                         sv1.x, sv1.y, sv1.z, sv1.w,
                         sv2.x, sv2.y, sv2.z, sv2.w,
                         sv3.x, sv3.y, sv3.z, sv3.w};

    const unsigned short* wl = &Wlds[((unsigned)(nbase << 6) + (unsigned)lane) << 3];
    const float* bb = &Blds[(nbase << 5) + (h << 4)];

    float msg[8];

    // ---- half A: n = nbase + kk, result kept by h==0 lanes ----
    #pragma unroll
    for (int kk = 0; kk < 8; ++kk) {
        f32x16 acc;
        #pragma unroll
        for (int r = 0; r < 16; ++r) acc[r] = bb[kk * 32 + r];   // 4x ds_read_b128 (broadcast)
        const short8 afrag = *reinterpret_cast<const short8*>(wl + kk * 512);
        acc = __builtin_amdgcn_mfma_f32_32x32x16_bf16(afrag, bfrag, acc, 0, 0, 0);
        float p0 = 0.f, p1 = 0.f, p2 = 0.f, p3 = 0.f;
        #pragma unroll
        for (int r = 0; r < 16; r += 4) {
            p0 = fmaf(fmaxf(acc[r+0], 0.f), s[r+0], p0);
            p1 = fmaf(fmaxf(acc[r+1], 0.f), s[r+1], p1);
            p2 = fmaf(fmaxf(acc[r+2], 0.f), s[r+2], p2);
            p3 = fmaf(fmaxf(acc[r+3], 0.f), s[r+3], p3);
        }
        float p = (p0 + p1) + (p2 + p3);
        p += __shfl_xor(p, 32);
        msg[kk] = p;
    }
    if (h == 0) {
        float* op = out + row * 32 + nbase;
        *reinterpret_cast<float4*>(op)     = make_float4(msg[0], msg[1], msg[2], msg[3]);
        *reinterpret_cast<float4*>(op + 4) = make_float4(msg[4], msg[5], msg[6], msg[7]);
    }

    // ---- half B: n = nbase + 8 + kk, result kept by h==1 lanes ----
    #pragma unroll
    for (int kk = 0; kk < 8; ++kk) {
        f32x16 acc;
        #pragma unroll
        for (int r = 0; r < 16; ++r) acc[r] = bb[(8 + kk) * 32 + r];
        const short8 afrag = *reinterpret_cast<const short8*>(wl + (8 + kk) * 512);
        acc = __builtin_amdgcn_mfma_f32_32x32x16_bf16(afrag, bfrag, acc, 0, 0, 0);
        float p0 = 0.f, p1 = 0.f, p2 = 0.f, p3 = 0.f;
        #pragma unroll
        for (int r = 0; r < 16; r += 4) {
            p0 = fmaf(fmaxf(acc[r+0], 0.f), s[r+0], p0);
            p1 = fmaf(fmaxf(acc[r+1], 0.f), s[r+1], p1);
            p2 = fmaf(fmaxf(acc[r+2], 0.f), s[r+2], p2);
            p3 = fmaf(fmaxf(acc[r+3], 0.f), s[r+3], p3);
        }
        float p = (p0 + p1) + (p2 + p3);
        p += __shfl_xor(p, 32);
        msg[kk] = p;
    }
    if (h == 1) {
        float* op = out + row * 32 + nbase + 8;
        *reinterpret_cast<float4*>(op)     = make_float4(msg[0], msg[1], msg[2], msg[3]);
        *reinterpret_cast<float4*>(op + 4) = make_float4(msg[4], msg[5], msg[6], msg[7]);
    }
}

extern "C" void kernel_launch(void* const* d_in, const int* in_sizes, int n_in,
                              void* d_out, int out_size, void* d_ws, size_t ws_size,
                              hipStream_t stream) {
    (void)in_sizes; (void)n_in; (void)d_ws; (void)ws_size; (void)out_size;
    const float* states = (const float*)d_in[0];
    const float* edges  = (const float*)d_in[1];
    const float* W      = (const float*)d_in[2];
    const float* bias   = (const float*)d_in[3];
    float* out          = (float*)d_out;

    hipLaunchKernelGGL(edgenet_kernel, dim3(512), dim3(512), 0, stream,
                       states, edges, W, bias, out);
}